// Round 4
// baseline (1984.583 us; speedup 1.0000x reference)
//
// v3: identical to v2 (r2/r3 were container infra failures, kernel never ran)
#include <hip/hip_runtime.h>

#define TRIP 1533   // 3*511

// ---------------- W repack: Wr[(k*CIN+c)*COUT + o] = W[o][c][k] ----------------
template<int CIN, int COUT>
__global__ void k_repack(const float* __restrict__ W, float* __restrict__ Wr) {
    int id = blockIdx.x * 256 + threadIdx.x;
    if (id >= 3 * CIN * COUT) return;
    int o = id % COUT, kk = id / COUT;
    int k = kk / CIN, c = kk % CIN;
    Wr[id] = W[(o * CIN + c) * 3 + k];
}

// ---------------- transpose trees [Bc][128][512] -> t0 [Bc][512][128] ----------------
__global__ void k_transpose(const float* __restrict__ in, float* __restrict__ out) {
    __shared__ float tl[64][129];
    int b = blockIdx.z, n0 = blockIdx.x * 64, t = threadIdx.x;
    int n = t & 63;
    for (int c = t >> 6; c < 128; c += 4)
        tl[n][c] = in[((size_t)b * 128 + c) * 512 + n0 + n];
    __syncthreads();
    int cq = t & 31;
    for (int nr = t >> 5; nr < 64; nr += 8) {
        float4 v = { tl[nr][cq*4+0], tl[nr][cq*4+1], tl[nr][cq*4+2], tl[nr][cq*4+3] };
        *(float4*)&out[((size_t)b * 512 + n0 + nr) * 128 + cq * 4] = v;
    }
}

// ---------------- zero node-0 row of activation buffers ----------------
__global__ void k_zero_row0(float* __restrict__ o1, float* __restrict__ o2, float* __restrict__ o3) {
    int b = blockIdx.x, t = threadIdx.x;
    if (t < 256) o1[(size_t)b * 512 * 256 + t] = 0.f;
    if (t < 128) o2[(size_t)b * 512 * 128 + t] = 0.f;
    if (t < 64)  o3[(size_t)b * 512 * 64  + t] = 0.f;
}

// ---------------- tiled conv-as-GEMM with inline norm+leaky on input ----------------
// Out[b][node][o] = sum_{kk} Wr[kk][o] * f(xin[b][idx[3(node-1)+k]][c]),  kk = k*CIN+c
// f = identity (layer 1) or leaky((x-mean)*inv) from sIn stats.
// Also accumulates per-tree sum / sumsq of raw output (incl. bias) into sOut.
template<int CIN, int COUT, int MT, bool NORM_IN>
__global__ __launch_bounds__(256) void k_conv(
    const float* __restrict__ xin, const int* __restrict__ idx,
    const float* __restrict__ Wr, const float* __restrict__ bias,
    float* __restrict__ out, const float* __restrict__ sIn, float* __restrict__ sOut)
{
    constexpr int NT = 128;
    constexpr int MH = MT / 64;     // 2 (MT=128) or 1 (MT=64)
    constexpr int K  = 3 * CIN;
    __shared__ float Wl[32][MT];
    __shared__ float Gl[32][NT + 4];
    __shared__ int   il[3 * NT];
    __shared__ float rs[4], rq[4];

    const int b   = blockIdx.z;
    const int mo0 = blockIdx.y * MT;
    const int n0  = 1 + blockIdx.x * NT;
    const int t   = threadIdx.x;
    const int tm  = t & 15, tn = t >> 4;

    float mean = 0.f, inv = 1.f;
    if (NORM_IN) {
        float s = sIn[b * 2], ss = sIn[b * 2 + 1];
        const float nel = (float)(CIN * 512);
        float mu  = s / nel;
        float var = (ss - nel * mu * mu) / (nel - 1.f);
        mean = mu; inv = 1.f / (sqrtf(var) + 1e-5f);
    }

    for (int i = t; i < 3 * NT; i += 256) {
        int n = i / 3;
        il[i] = (n0 + n <= 511) ? idx[b * TRIP + 3 * (n0 - 1) + i] : 0;
    }
    __syncthreads();

    float acc[MH][2][4][4] = {};

    const int nloc = t & 127;
    const int ib   = (t >> 7) * 4;

    for (int ch = 0; ch < K / 32; ++ch) {
        const int kk0 = ch * 32;
        const int ks  = kk0 / CIN, c0 = kk0 % CIN;
        // stage W chunk [32][MT]
        for (int f = t; f < 32 * MT / 4; f += 256) {
            int row = f / (MT / 4), col4 = f % (MT / 4);
            *(float4*)&Wl[row][col4 * 4] =
                *(const float4*)&Wr[(size_t)(kk0 + row) * COUT + mo0 + col4 * 4];
        }
        // stage G chunk [32][NT] (transposed: Gl[kk_local][n])
        const int node = il[nloc * 3 + ks];
        const float* src = &xin[((size_t)b * 512 + node) * CIN + c0];
        #pragma unroll
        for (int p = 0; p < 4; ++p) {
            int i0 = ib + p * 8;
            float4 v = *(const float4*)&src[i0];
            if (NORM_IN) {
                v.x = (v.x - mean) * inv; v.x = v.x >= 0.f ? v.x : 0.01f * v.x;
                v.y = (v.y - mean) * inv; v.y = v.y >= 0.f ? v.y : 0.01f * v.y;
                v.z = (v.z - mean) * inv; v.z = v.z >= 0.f ? v.z : 0.01f * v.z;
                v.w = (v.w - mean) * inv; v.w = v.w >= 0.f ? v.w : 0.01f * v.w;
            }
            Gl[i0 + 0][nloc] = v.x; Gl[i0 + 1][nloc] = v.y;
            Gl[i0 + 2][nloc] = v.z; Gl[i0 + 3][nloc] = v.w;
        }
        __syncthreads();
        // compute
        #pragma unroll 8
        for (int kc = 0; kc < 32; ++kc) {
            float a[MH][4], bb[2][4];
            #pragma unroll
            for (int ih = 0; ih < MH; ++ih)
                *(float4*)&a[ih][0] = *(const float4*)&Wl[kc][ih * 64 + tm * 4];
            #pragma unroll
            for (int jh = 0; jh < 2; ++jh)
                *(float4*)&bb[jh][0] = *(const float4*)&Gl[kc][jh * 64 + tn * 4];
            #pragma unroll
            for (int ih = 0; ih < MH; ++ih)
                #pragma unroll
                for (int i = 0; i < 4; ++i)
                    #pragma unroll
                    for (int jh = 0; jh < 2; ++jh)
                        #pragma unroll
                        for (int j = 0; j < 4; ++j)
                            acc[ih][jh][i][j] = fmaf(a[ih][i], bb[jh][j], acc[ih][jh][i][j]);
        }
        __syncthreads();
    }

    // epilogue: bias, store raw, partial stats
    float bi[MH][4];
    #pragma unroll
    for (int ih = 0; ih < MH; ++ih)
        #pragma unroll
        for (int i = 0; i < 4; ++i)
            bi[ih][i] = bias[mo0 + ih * 64 + tm * 4 + i];

    float lsum = 0.f, lss = 0.f;
    #pragma unroll
    for (int jh = 0; jh < 2; ++jh)
        #pragma unroll
        for (int j = 0; j < 4; ++j) {
            int jg = n0 + jh * 64 + tn * 4 + j;
            if (jg <= 511) {
                #pragma unroll
                for (int ih = 0; ih < MH; ++ih) {
                    float4 v;
                    v.x = acc[ih][jh][0][j] + bi[ih][0];
                    v.y = acc[ih][jh][1][j] + bi[ih][1];
                    v.z = acc[ih][jh][2][j] + bi[ih][2];
                    v.w = acc[ih][jh][3][j] + bi[ih][3];
                    *(float4*)&out[((size_t)b * 512 + jg) * COUT + mo0 + ih * 64 + tm * 4] = v;
                    lsum += v.x + v.y + v.z + v.w;
                    lss  += v.x * v.x + v.y * v.y + v.z * v.z + v.w * v.w;
                }
            }
        }

    #pragma unroll
    for (int off = 32; off > 0; off >>= 1) {
        lsum += __shfl_down(lsum, off);
        lss  += __shfl_down(lss, off);
    }
    int w = t >> 6;
    if ((t & 63) == 0) { rs[w] = lsum; rq[w] = lss; }
    __syncthreads();
    if (t == 0) {
        atomicAdd(&sOut[b * 2],     rs[0] + rs[1] + rs[2] + rs[3]);
        atomicAdd(&sOut[b * 2 + 1], rq[0] + rq[1] + rq[2] + rq[3]);
    }
}

// ---------------- max-pool (with final norm affine) + FC1 + FC2 ----------------
__global__ __launch_bounds__(256) void k_pool_fc(
    const float* __restrict__ x,      // [Bc][512][64] raw conv3 output
    const float* __restrict__ stats,  // [Bc][2]
    const float* __restrict__ Wf1, const float* __restrict__ bf1,
    const float* __restrict__ Wf2, const float* __restrict__ bf2,
    float* __restrict__ outp)
{
    __shared__ float cm[4][64];
    __shared__ float pool[64];
    __shared__ float h[32];
    int b = blockIdx.x, t = threadIdx.x;
    int c = t & 63, g = t >> 6;
    float m = -1e30f;
    for (int n = 1 + g; n <= 511; n += 4)
        m = fmaxf(m, x[((size_t)b * 512 + n) * 64 + c]);
    cm[g][c] = m;
    __syncthreads();
    if (t < 64) {
        float mm = fmaxf(fmaxf(cm[0][t], cm[1][t]), fmaxf(cm[2][t], cm[3][t]));
        mm = fmaxf(mm, 0.f);  // node-0 zero column participates in the max
        float s = stats[b * 2], ss = stats[b * 2 + 1];
        const float nel = 64.f * 512.f;
        float mu  = s / nel;
        float var = (ss - nel * mu * mu) / (nel - 1.f);
        float inv = 1.f / (sqrtf(var) + 1e-5f);
        pool[t] = (mm - mu) * inv;
    }
    __syncthreads();
    if (t < 32) {
        float acc = bf1[t];
        for (int cc = 0; cc < 64; ++cc) acc += pool[cc] * Wf1[t * 64 + cc];
        h[t] = acc >= 0.f ? acc : 0.01f * acc;
    }
    __syncthreads();
    if (t == 0) {
        float acc = bf2[0];
        for (int j = 0; j < 32; ++j) acc += h[j] * Wf2[j];
        outp[b] = acc;
    }
}

extern "C" void kernel_launch(void* const* d_in, const int* in_sizes, int n_in,
                              void* d_out, int out_size, void* d_ws, size_t ws_size,
                              hipStream_t stream)
{
    const float* trees = (const float*)d_in[0];
    const int*   idx32 = (const int*)d_in[1];   // harness passes integer inputs as int32
    const float* W1  = (const float*)d_in[2];
    const float* b1  = (const float*)d_in[3];
    const float* W2  = (const float*)d_in[4];
    const float* b2  = (const float*)d_in[5];
    const float* W3  = (const float*)d_in[6];
    const float* b3  = (const float*)d_in[7];
    const float* Wf1 = (const float*)d_in[8];
    const float* bf1 = (const float*)d_in[9];
    const float* Wf2 = (const float*)d_in[10];
    const float* bf2 = (const float*)d_in[11];
    float* outp = (float*)d_out;
    char*  ws   = (char*)d_ws;

    // fixed workspace: stats + repacked weights
    float* stats = (float*)ws;                  // 3*512*2*4 = 12288 B
    float* Wr1   = (float*)(ws + 12288);        // 384*256*4 = 393216
    float* Wr2   = (float*)(ws + 405504);       // 768*128*4 = 393216
    float* Wr3   = (float*)(ws + 798720);       // 384*64*4  = 98304
    char*  chunkBase = ws + 897024;
    float* s0 = stats, *s1 = stats + 1024, *s2 = stats + 2048;

    // adaptive batch chunking: per-chunk bytes = Bc * (128+256+64)*512*4 = Bc*917504
    const size_t fixedB = 897024;
    int Bc = 512;
    while (Bc > 1 && fixedB + (size_t)Bc * 917504 > ws_size) Bc >>= 1;

    hipMemsetAsync(stats, 0, 12288, stream);
    k_repack<128, 256><<<384, 256, 0, stream>>>(W1, Wr1);
    k_repack<256, 128><<<384, 256, 0, stream>>>(W2, Wr2);
    k_repack<128, 64><<<96, 256, 0, stream>>>(W3, Wr3);

    float* t0   = (float*)chunkBase;                              // Bc*512*128 f32 (also out2)
    float* out1 = (float*)(chunkBase + (size_t)Bc * 262144);      // Bc*512*256 f32
    float* out3 = (float*)(chunkBase + (size_t)Bc * 786432);      // Bc*512*64  f32

    for (int c0 = 0; c0 < 512; c0 += Bc) {
        const float* treesC = trees + (size_t)c0 * 128 * 512;
        const int*   idxC   = idx32 + (size_t)c0 * TRIP;

        k_transpose<<<dim3(8, 1, Bc), 256, 0, stream>>>(treesC, t0);
        k_conv<128, 256, 128, false><<<dim3(4, 2, Bc), 256, 0, stream>>>(
            t0, idxC, Wr1, b1, out1, nullptr, s0 + c0 * 2);
        k_zero_row0<<<Bc, 256, 0, stream>>>(out1, t0, out3);
        k_conv<256, 128, 128, true><<<dim3(4, 1, Bc), 256, 0, stream>>>(
            out1, idxC, Wr2, b2, t0, s0 + c0 * 2, s1 + c0 * 2);
        k_conv<128, 64, 64, true><<<dim3(4, 1, Bc), 256, 0, stream>>>(
            t0, idxC, Wr3, b3, out3, s1 + c0 * 2, s2 + c0 * 2);
        k_pool_fc<<<Bc, 256, 0, stream>>>(out3, s2 + c0 * 2, Wf1, bf1, Wf2, bf2, outp + c0);
    }

    (void)in_sizes; (void)n_in; (void)out_size; (void)ws_size;
}

// Round 6
// 699.728 us; speedup vs baseline: 2.8362x; 2.8362x over previous
//
// v5: identical to v4 (r5 was a container infra failure, kernel never ran)
#include <hip/hip_runtime.h>

#define TRIP 1533   // 3*511

typedef __attribute__((ext_vector_type(8))) short bf16x8;
typedef __attribute__((ext_vector_type(4))) float f32x4;

__device__ __forceinline__ void split2(float a, float b, unsigned& h, unsigned& l) {
    unsigned ba = __float_as_uint(a), bb = __float_as_uint(b);
    unsigned ha = ba & 0xFFFF0000u, hb = bb & 0xFFFF0000u;
    float ra = a - __uint_as_float(ha);
    float rb = b - __uint_as_float(hb);
    h = (ba >> 16) | hb;
    l = (__float_as_uint(ra) >> 16) | (__float_as_uint(rb) & 0xFFFF0000u);
}

// ---------------- W repack+split: WtHi/Lo[o][ks*CIN+c] = split(W[o][c][ks]) ----------------
template<int CIN, int COUT>
__global__ void k_repackW(const float* __restrict__ W,
                          unsigned short* __restrict__ Hi, unsigned short* __restrict__ Lo) {
    int id = blockIdx.x * 256 + threadIdx.x;
    if (id >= 3 * CIN * COUT) return;
    int o = id / (3 * CIN), kk = id % (3 * CIN);
    int ks = kk / CIN, c = kk % CIN;
    float v = W[(o * CIN + c) * 3 + ks];
    unsigned b = __float_as_uint(v);
    unsigned h = b & 0xFFFF0000u;
    float r = v - __uint_as_float(h);
    Hi[id] = (unsigned short)(b >> 16);
    Lo[id] = (unsigned short)(__float_as_uint(r) >> 16);
}

// ---------------- transpose trees [Bc][128][512] -> t0 [Bc][512][128] ----------------
__global__ void k_transpose(const float* __restrict__ in, float* __restrict__ out) {
    __shared__ float tl[64][129];
    int b = blockIdx.z, n0 = blockIdx.x * 64, t = threadIdx.x;
    int n = t & 63;
    for (int c = t >> 6; c < 128; c += 4)
        tl[n][c] = in[((size_t)b * 128 + c) * 512 + n0 + n];
    __syncthreads();
    int cq = t & 31;
    for (int nr = t >> 5; nr < 64; nr += 8) {
        float4 v = { tl[nr][cq*4+0], tl[nr][cq*4+1], tl[nr][cq*4+2], tl[nr][cq*4+3] };
        *(float4*)&out[((size_t)b * 512 + n0 + nr) * 128 + cq * 4] = v;
    }
}

// ---------------- zero node-0 row of activation buffers ----------------
__global__ void k_zero_row0(float* __restrict__ o1, float* __restrict__ o2, float* __restrict__ o3) {
    int b = blockIdx.x, t = threadIdx.x;
    if (t < 256) o1[(size_t)b * 512 * 256 + t] = 0.f;
    if (t < 128) o2[(size_t)b * 512 * 128 + t] = 0.f;
    if (t < 64)  o3[(size_t)b * 512 * 64  + t] = 0.f;
}

// ---------------- MFMA conv: Out[b][n][o] = sum_kk f(G)[n][kk] * W[kk][o] ----------------
// 4 waves (2 node x 2 och), wave tile 64 x (OCH_T/2), 16x16x32 bf16 MFMA, hi/lo 3-product.
template<int CIN, int COUT, int OCH_T, bool NORM_IN>
__global__ __launch_bounds__(256) void k_convmfma(
    const float* __restrict__ xin, const int* __restrict__ idx,
    const unsigned short* __restrict__ WHi, const unsigned short* __restrict__ WLo,
    const float* __restrict__ bias, float* __restrict__ out,
    const float* __restrict__ sIn, float* __restrict__ sOut)
{
    constexpr int K  = 3 * CIN;
    constexpr int NK = K / 32;
    constexpr int N_ = OCH_T / 32;   // B-frags per wave
    constexpr int OH = OCH_T / 2;    // wave och tile

    __shared__ unsigned short Gh[128][40], Gl[128][40];
    __shared__ unsigned short Wh[OCH_T][40], Wl[OCH_T][40];
    __shared__ int   il[384];
    __shared__ float rs[4], rq[4];

    const int b    = blockIdx.z;
    const int och0 = blockIdx.y * OCH_T;
    const int n0   = 1 + blockIdx.x * 128;
    const int t    = threadIdx.x;
    const int lane = t & 63, wave = t >> 6;
    const int wm = wave >> 1, wn = wave & 1;
    const int l15 = lane & 15, l16 = lane >> 4;

    float mean = 0.f, inv = 1.f;
    if (NORM_IN) {
        float s = sIn[b * 2], ss = sIn[b * 2 + 1];
        const float nel = (float)(CIN * 512);
        float mu  = s / nel;
        float var = (ss - nel * mu * mu) / (nel - 1.f);
        mean = mu; inv = 1.f / (sqrtf(var) + 1e-5f);
    }

    for (int i = t; i < 384; i += 256) {
        int n = i / 3;
        il[i] = (n0 + n <= 511) ? idx[b * TRIP + 3 * (n0 - 1) + i] : 0;
    }

    f32x4 acc[4][N_] = {};

    const int nodeL = t >> 1;
    const int cb    = (t & 1) * 16;

    for (int ch = 0; ch < NK; ++ch) {
        const int kk0 = ch * 32;
        const int ks  = kk0 / CIN, c0 = kk0 % CIN;
        __syncthreads();   // previous compute done reading LDS (also covers il on ch==0)

        // ---- stage G (gather + transform + split) ----
        {
            const float* src = &xin[((size_t)b * 512 + il[nodeL * 3 + ks]) * CIN + c0 + cb];
            #pragma unroll
            for (int i = 0; i < 4; ++i) {
                float4 v = *(const float4*)&src[i * 4];
                if (NORM_IN) {
                    v.x = (v.x - mean) * inv; v.x = v.x >= 0.f ? v.x : 0.01f * v.x;
                    v.y = (v.y - mean) * inv; v.y = v.y >= 0.f ? v.y : 0.01f * v.y;
                    v.z = (v.z - mean) * inv; v.z = v.z >= 0.f ? v.z : 0.01f * v.z;
                    v.w = (v.w - mean) * inv; v.w = v.w >= 0.f ? v.w : 0.01f * v.w;
                }
                unsigned h01, l01, h23, l23;
                split2(v.x, v.y, h01, l01);
                split2(v.z, v.w, h23, l23);
                *(uint2*)&Gh[nodeL][cb + i * 4] = make_uint2(h01, h23);
                *(uint2*)&Gl[nodeL][cb + i * 4] = make_uint2(l01, l23);
            }
        }
        // ---- stage W (plain bf16 copy) ----
        for (int f = t; f < OCH_T * 4; f += 256) {
            int och = f >> 2, s = (f & 3) * 8;
            size_t g = (size_t)(och0 + och) * K + kk0 + s;
            *(uint4*)&Wh[och][s] = *(const uint4*)&WHi[g];
            *(uint4*)&Wl[och][s] = *(const uint4*)&WLo[g];
        }
        __syncthreads();

        // ---- fragments + MFMA ----
        bf16x8 Ah[4], Al[4], Bh[N_], Bl[N_];
        #pragma unroll
        for (int mi = 0; mi < 4; ++mi) {
            int nl = wm * 64 + mi * 16 + l15;
            Ah[mi] = *(const bf16x8*)&Gh[nl][l16 * 8];
            Al[mi] = *(const bf16x8*)&Gl[nl][l16 * 8];
        }
        #pragma unroll
        for (int ni = 0; ni < N_; ++ni) {
            int ol = wn * OH + ni * 16 + l15;
            Bh[ni] = *(const bf16x8*)&Wh[ol][l16 * 8];
            Bl[ni] = *(const bf16x8*)&Wl[ol][l16 * 8];
        }
        #pragma unroll
        for (int mi = 0; mi < 4; ++mi)
            #pragma unroll
            for (int ni = 0; ni < N_; ++ni) {
                acc[mi][ni] = __builtin_amdgcn_mfma_f32_16x16x32_bf16(Ah[mi], Bh[ni], acc[mi][ni], 0, 0, 0);
                acc[mi][ni] = __builtin_amdgcn_mfma_f32_16x16x32_bf16(Ah[mi], Bl[ni], acc[mi][ni], 0, 0, 0);
                acc[mi][ni] = __builtin_amdgcn_mfma_f32_16x16x32_bf16(Al[mi], Bh[ni], acc[mi][ni], 0, 0, 0);
            }
    }

    // ---- epilogue: bias, store fp32, per-tree stats ----
    float lsum = 0.f, lss = 0.f;
    #pragma unroll
    for (int ni = 0; ni < N_; ++ni) {
        int ol = wn * OH + ni * 16 + l15;
        float bi = bias[och0 + ol];
        #pragma unroll
        for (int mi = 0; mi < 4; ++mi) {
            #pragma unroll
            for (int r = 0; r < 4; ++r) {
                int nl = wm * 64 + mi * 16 + l16 * 4 + r;
                int ng = n0 + nl;
                if (ng <= 511) {
                    float v = acc[mi][ni][r] + bi;
                    out[((size_t)b * 512 + ng) * COUT + och0 + ol] = v;
                    lsum += v; lss += v * v;
                }
            }
        }
    }

    #pragma unroll
    for (int off = 32; off > 0; off >>= 1) {
        lsum += __shfl_down(lsum, off);
        lss  += __shfl_down(lss, off);
    }
    if (lane == 0) { rs[wave] = lsum; rq[wave] = lss; }
    __syncthreads();
    if (t == 0) {
        atomicAdd(&sOut[b * 2],     rs[0] + rs[1] + rs[2] + rs[3]);
        atomicAdd(&sOut[b * 2 + 1], rq[0] + rq[1] + rq[2] + rq[3]);
    }
}

// ---------------- max-pool (with final norm affine) + FC1 + FC2 ----------------
__global__ __launch_bounds__(256) void k_pool_fc(
    const float* __restrict__ x,      // [Bc][512][64] raw conv3 output
    const float* __restrict__ stats,  // [Bc][2]
    const float* __restrict__ Wf1, const float* __restrict__ bf1,
    const float* __restrict__ Wf2, const float* __restrict__ bf2,
    float* __restrict__ outp)
{
    __shared__ float cm[4][64];
    __shared__ float pool[64];
    __shared__ float h[32];
    int b = blockIdx.x, t = threadIdx.x;
    int c = t & 63, g = t >> 6;
    float m = -1e30f;
    for (int n = 1 + g; n <= 511; n += 4)
        m = fmaxf(m, x[((size_t)b * 512 + n) * 64 + c]);
    cm[g][c] = m;
    __syncthreads();
    if (t < 64) {
        float mm = fmaxf(fmaxf(cm[0][t], cm[1][t]), fmaxf(cm[2][t], cm[3][t]));
        mm = fmaxf(mm, 0.f);  // node-0 zero column participates in the max
        float s = stats[b * 2], ss = stats[b * 2 + 1];
        const float nel = 64.f * 512.f;
        float mu  = s / nel;
        float var = (ss - nel * mu * mu) / (nel - 1.f);
        float inv = 1.f / (sqrtf(var) + 1e-5f);
        pool[t] = (mm - mu) * inv;
    }
    __syncthreads();
    if (t < 32) {
        float acc = bf1[t];
        for (int cc = 0; cc < 64; ++cc) acc += pool[cc] * Wf1[t * 64 + cc];
        h[t] = acc >= 0.f ? acc : 0.01f * acc;
    }
    __syncthreads();
    if (t == 0) {
        float acc = bf2[0];
        for (int j = 0; j < 32; ++j) acc += h[j] * Wf2[j];
        outp[b] = acc;
    }
}

extern "C" void kernel_launch(void* const* d_in, const int* in_sizes, int n_in,
                              void* d_out, int out_size, void* d_ws, size_t ws_size,
                              hipStream_t stream)
{
    const float* trees = (const float*)d_in[0];
    const int*   idx32 = (const int*)d_in[1];
    const float* W1  = (const float*)d_in[2];
    const float* b1  = (const float*)d_in[3];
    const float* W2  = (const float*)d_in[4];
    const float* b2  = (const float*)d_in[5];
    const float* W3  = (const float*)d_in[6];
    const float* b3  = (const float*)d_in[7];
    const float* Wf1 = (const float*)d_in[8];
    const float* bf1 = (const float*)d_in[9];
    const float* Wf2 = (const float*)d_in[10];
    const float* bf2 = (const float*)d_in[11];
    float* outp = (float*)d_out;
    char*  ws   = (char*)d_ws;

    // fixed workspace: stats + split weights (bf16)
    float*          stats = (float*)ws;                         // 12288 B
    unsigned short* w1h = (unsigned short*)(ws + 12288);        // 256*384*2 = 196608
    unsigned short* w1l = (unsigned short*)(ws + 208896);       // 196608
    unsigned short* w2h = (unsigned short*)(ws + 405504);       // 128*768*2 = 196608
    unsigned short* w2l = (unsigned short*)(ws + 602112);       // 196608
    unsigned short* w3h = (unsigned short*)(ws + 798720);       // 64*384*2 = 49152
    unsigned short* w3l = (unsigned short*)(ws + 847872);       // 49152
    char* chunkBase = ws + 897024;
    float* s0 = stats, *s1 = stats + 1024, *s2 = stats + 2048;

    // adaptive batch chunking: per-chunk bytes = Bc * (128+256+64)*512*4 = Bc*917504
    const size_t fixedB = 897024;
    int Bc = 512;
    while (Bc > 1 && fixedB + (size_t)Bc * 917504 > ws_size) Bc >>= 1;

    hipMemsetAsync(stats, 0, 12288, stream);
    k_repackW<128, 256><<<384, 256, 0, stream>>>(W1, w1h, w1l);
    k_repackW<256, 128><<<384, 256, 0, stream>>>(W2, w2h, w2l);
    k_repackW<128, 64><<<96, 256, 0, stream>>>(W3, w3h, w3l);

    float* t0   = (float*)chunkBase;                              // Bc*512*128 f32 (also out2)
    float* out1 = (float*)(chunkBase + (size_t)Bc * 262144);      // Bc*512*256 f32
    float* out3 = (float*)(chunkBase + (size_t)Bc * 786432);      // Bc*512*64  f32

    for (int c0 = 0; c0 < 512; c0 += Bc) {
        const float* treesC = trees + (size_t)c0 * 128 * 512;
        const int*   idxC   = idx32 + (size_t)c0 * TRIP;

        k_transpose<<<dim3(8, 1, Bc), 256, 0, stream>>>(treesC, t0);
        k_convmfma<128, 256, 128, false><<<dim3(4, 2, Bc), 256, 0, stream>>>(
            t0, idxC, w1h, w1l, b1, out1, nullptr, s0 + c0 * 2);
        k_zero_row0<<<Bc, 256, 0, stream>>>(out1, t0, out3);
        k_convmfma<256, 128, 128, true><<<dim3(4, 1, Bc), 256, 0, stream>>>(
            out1, idxC, w2h, w2l, b2, t0, s0 + c0 * 2, s1 + c0 * 2);
        k_convmfma<128, 64, 64, true><<<dim3(4, 1, Bc), 256, 0, stream>>>(
            t0, idxC, w3h, w3l, b3, out3, s1 + c0 * 2, s2 + c0 * 2);
        k_pool_fc<<<Bc, 256, 0, stream>>>(out3, s2 + c0 * 2, Wf1, bf1, Wf2, bf2, outp + c0);
    }

    (void)in_sizes; (void)n_in; (void)out_size; (void)ws_size;
}